// Round 5
// baseline (388.465 us; speedup 1.0000x reference)
//
#include <hip/hip_runtime.h>
#include <hip/hip_bf16.h>

#define N_NODES 50000
#define N_EDGES 600000
#define D 128
#define NB_SCAN 196  // ceil(50000/256)

constexpr float AVG_D_LOG = 1.6094379124341003f;  // log(5)
constexpr float EPS_V = 1e-5f;

// ---- workspace byte offsets (total ~93.1 MB)
#define PQ_B     0ul           // bf16 [50000][256]  P|Q rows     = 25,600,000
#define AGG_B    25600000ul    // bf16 [50000][512]  mean|max|min|std = 51,200,000
#define HBF_B    76800000ul    // bf16 [50000][128]
#define WPRET2_B 89600000ul    // bf16 [256][128]   (P cols | Q cols, [n][k])
#define WPOSTT_B 89665536ul    // bf16 [128][1664]
#define WMIXT_B  90091520ul    // bf16 [128][128]
#define DEGC_B   90124288ul    // int  [50000]
#define OFF_B    90324288ul    // int  [50016]
#define CUR_B    90524352ul    // int  [50000]
#define SRCS_B   90724352ul    // int  [600000]  src ids in dst-sorted order
#define BSUM_B   93124352ul    // int  [256]

typedef __attribute__((ext_vector_type(8))) short bf16x8;
typedef __attribute__((ext_vector_type(4))) float f32x4;

__device__ __forceinline__ short f2b(float f) {
    unsigned u = __builtin_bit_cast(unsigned, f);
    u += 0x7fffu + ((u >> 16) & 1u);   // RNE
    return (short)(u >> 16);
}
__device__ __forceinline__ unsigned pk2(float a, float b) {
    return (unsigned)(unsigned short)f2b(a) | ((unsigned)(unsigned short)f2b(b) << 16);
}
__device__ __forceinline__ float blo(unsigned u) { return __uint_as_float(u << 16); }
__device__ __forceinline__ float bhi(unsigned u) { return __uint_as_float(u & 0xffff0000u); }

// ---------------------------------------------------------------- prep
__global__ __launch_bounds__(256) void prep_kernel(
    const float* __restrict__ h, const float* __restrict__ Wpre,
    const float* __restrict__ Wpost, const float* __restrict__ Wmix,
    short* __restrict__ hbf, short* __restrict__ wpreT2,
    short* __restrict__ wpostT, short* __restrict__ wmixT,
    int* __restrict__ degc, int* __restrict__ cursor)
{
    long i = (long)blockIdx.x * 256 + threadIdx.x;
    if (i < 6400000) { hbf[i] = f2b(h[i]); return; }
    i -= 6400000;
    if (i < 32768) {  // wpreT2[n][k]: n<128 -> Wpre[k][n] (top); n>=128 -> Wpre[k+128][n-128]
        int n = i >> 7, k = i & 127;
        float v = (n < 128) ? Wpre[k * 128 + n] : Wpre[(k + 128) * 128 + (n - 128)];
        wpreT2[n * 128 + k] = f2b(v);
        return;
    }
    i -= 32768;
    if (i < 212992) { int k = i >> 7, n = i & 127; wpostT[n * 1664 + k] = f2b(Wpost[k * 128 + n]); return; }
    i -= 212992;
    if (i < 16384) { int k = i >> 7, n = i & 127; wmixT[n * 128 + k] = f2b(Wmix[k * 128 + n]); return; }
    i -= 16384;
    if (i < N_NODES) { degc[i] = 0; return; }
    i -= N_NODES;
    if (i < N_NODES) cursor[i] = 0;
}

// ---------------------------------------------------------------- degree histogram
__global__ __launch_bounds__(256) void hist_kernel(const int* __restrict__ edst, int* __restrict__ degc) {
    int e = blockIdx.x * 256 + threadIdx.x;
    if (e < N_EDGES) atomicAdd(&degc[edst[e]], 1);
}

// ---------------------------------------------------------------- scan
__global__ __launch_bounds__(256) void scan1_kernel(const int* __restrict__ degc, int* __restrict__ bsum) {
    int n = blockIdx.x * 256 + threadIdx.x;
    int v = (n < N_NODES) ? degc[n] : 0;
#pragma unroll
    for (int o = 32; o > 0; o >>= 1) v += __shfl_down(v, o);
    __shared__ int w4[4];
    if ((threadIdx.x & 63) == 0) w4[threadIdx.x >> 6] = v;
    __syncthreads();
    if (threadIdx.x == 0) bsum[blockIdx.x] = w4[0] + w4[1] + w4[2] + w4[3];
}

// parallel exclusive scan of the 196 block sums (one block)
__global__ __launch_bounds__(256) void scan2_kernel(int* __restrict__ bsum, int* __restrict__ off) {
    __shared__ int sd[256];
    int tid = threadIdx.x;
    int v = (tid < NB_SCAN) ? bsum[tid] : 0;
    sd[tid] = v;
    __syncthreads();
    for (int o = 1; o < 256; o <<= 1) {
        int t = (tid >= o) ? sd[tid - o] : 0;
        __syncthreads();
        sd[tid] += t;
        __syncthreads();
    }
    if (tid < NB_SCAN) bsum[tid] = sd[tid] - v;   // exclusive
    if (tid == 0) off[N_NODES] = sd[255];         // total = N_EDGES
}

__global__ __launch_bounds__(256) void scan3_kernel(const int* __restrict__ degc,
                                                    const int* __restrict__ bsum, int* __restrict__ off) {
    __shared__ int sd[256];
    int tid = threadIdx.x;
    int n = blockIdx.x * 256 + tid;
    int v = (n < N_NODES) ? degc[n] : 0;
    sd[tid] = v;
    __syncthreads();
    for (int o = 1; o < 256; o <<= 1) {
        int t = (tid >= o) ? sd[tid - o] : 0;
        __syncthreads();
        sd[tid] += t;
        __syncthreads();
    }
    if (n < N_NODES) off[n] = sd[tid] - v + bsum[blockIdx.x];
}

// ---------------------------------------------------------------- scatter srcs into dst-sorted order
__global__ __launch_bounds__(256) void scatter_kernel(const int* __restrict__ esrc, const int* __restrict__ edst,
                                                      const int* __restrict__ off, int* __restrict__ cursor,
                                                      int* __restrict__ srcs) {
    int e = blockIdx.x * 256 + threadIdx.x;
    if (e < N_EDGES) {
        int d = edst[e];
        int p = off[d] + atomicAdd(&cursor[d], 1);
        srcs[p] = esrc[e];
    }
}

// ---------------------------------------------------------------- PQ = h @ [Wtop | Wbot] (+bias on Q)
__global__ __launch_bounds__(256) void gemm_pq_kernel(
    const short* __restrict__ hbf, const short* __restrict__ wpreT2,
    const float* __restrict__ bpre, short* __restrict__ PQ)
{
    __shared__ __align__(16) short As[128][72];
    __shared__ __align__(16) short Bs[256][72];

    const int tid = threadIdx.x;
    const int bn = blockIdx.x * 128;
    const int lane = tid & 63, wv = tid >> 6;
    const int lm = lane & 15, quad = lane >> 4;

    f32x4 acc[2][16];
#pragma unroll
    for (int a = 0; a < 2; a++)
#pragma unroll
        for (int b = 0; b < 16; b++) acc[a][b] = (f32x4){0.f, 0.f, 0.f, 0.f};

#pragma unroll
    for (int kc = 0; kc < 2; kc++) {
        __syncthreads();
#pragma unroll
        for (int t = 0; t < 4; t++) {
            int q = tid + t * 256;
            int m = q >> 3, seg = q & 7;
            int n = bn + m; if (n >= N_NODES) n = N_NODES - 1;
            *(int4*)&As[m][seg * 8] = *(const int4*)(hbf + (long)n * 128 + kc * 64 + seg * 8);
        }
#pragma unroll
        for (int t = 0; t < 8; t++) {
            int q = tid + t * 256;
            int n = q >> 3, seg = q & 7;
            *(int4*)&Bs[n][seg * 8] = *(const int4*)(wpreT2 + n * 128 + kc * 64 + seg * 8);
        }
        __syncthreads();
#pragma unroll
        for (int ks = 0; ks < 2; ks++) {
            const int ko = ks * 32 + quad * 8;
            bf16x8 a0 = *(const bf16x8*)&As[wv * 32 + lm][ko];
            bf16x8 a1 = *(const bf16x8*)&As[wv * 32 + 16 + lm][ko];
#pragma unroll
            for (int ct = 0; ct < 16; ct++) {
                bf16x8 b = *(const bf16x8*)&Bs[ct * 16 + lm][ko];
                acc[0][ct] = __builtin_amdgcn_mfma_f32_16x16x32_bf16(b, a0, acc[0][ct], 0, 0, 0);
                acc[1][ct] = __builtin_amdgcn_mfma_f32_16x16x32_bf16(b, a1, acc[1][ct], 0, 0, 0);
            }
        }
    }

    // epilogue: row = node, col 0-127 = P (no bias), 128-255 = Q (+bias)
#pragma unroll
    for (int rt = 0; rt < 2; rt++) {
        int row = wv * 32 + rt * 16 + lm;
        int n = bn + row;
        if (n >= N_NODES) continue;
        short* dst = PQ + (long)n * 256;
#pragma unroll
        for (int ct = 0; ct < 16; ct++) {
            int col = ct * 16 + quad * 4;
            float v0 = acc[rt][ct][0], v1 = acc[rt][ct][1], v2 = acc[rt][ct][2], v3 = acc[rt][ct][3];
            if (ct >= 8) {
                float4 bv = *(const float4*)(bpre + (col - 128));
                v0 += bv.x; v1 += bv.y; v2 += bv.z; v3 += bv.w;
            }
            int2 pkd; pkd.x = (int)pk2(v0, v1); pkd.y = (int)pk2(v2, v3);
            *(int2*)(dst + col) = pkd;
        }
    }
}

// ---------------------------------------------------------------- fused edge compute + stats: one wave per node
__global__ __launch_bounds__(256) void edgestats_kernel(
    const short* __restrict__ PQ, const int* __restrict__ srcs,
    const int* __restrict__ off, short* __restrict__ aggbf)
{
    const int wv = threadIdx.x >> 6, lane = threadIdx.x & 63;
    const int n = blockIdx.x * 4 + wv;            // grid 12500 * 4 waves = 50000
    const unsigned* Pb = (const unsigned*)PQ;     // u32 view: row = 128 u32 (P=0..63, Q=64..127)

    const int s0 = __builtin_amdgcn_readfirstlane(off[n]);
    const int s1 = __builtin_amdgcn_readfirstlane(off[n + 1]);

    unsigned qu = Pb[(long)n * 128 + 64 + lane];
    const float qa = blo(qu), qb = bhi(qu);

    float sA = 0.f, sB = 0.f, qA = 0.f, qB = 0.f;
    float mxA = -1e30f, mxB = -1e30f, mnA = 1e30f, mnB = 1e30f;

    int p = s0;
    for (; p + 4 <= s1; p += 4) {
        int i0 = srcs[p], i1 = srcs[p + 1], i2 = srcs[p + 2], i3 = srcs[p + 3];
        unsigned u0 = Pb[(long)i0 * 128 + lane];
        unsigned u1 = Pb[(long)i1 * 128 + lane];
        unsigned u2 = Pb[(long)i2 * 128 + lane];
        unsigned u3 = Pb[(long)i3 * 128 + lane];
#pragma unroll
        for (int j = 0; j < 4; j++) {
            unsigned u = (j == 0) ? u0 : (j == 1) ? u1 : (j == 2) ? u2 : u3;
            float a = blo(u) + qa; a = a > 0.f ? a : 0.f;
            float b = bhi(u) + qb; b = b > 0.f ? b : 0.f;
            sA += a; sB += b; qA += a * a; qB += b * b;
            mxA = fmaxf(mxA, a); mxB = fmaxf(mxB, b);
            mnA = fminf(mnA, a); mnB = fminf(mnB, b);
        }
    }
    for (; p < s1; p++) {
        unsigned u = Pb[(long)srcs[p] * 128 + lane];
        float a = blo(u) + qa; a = a > 0.f ? a : 0.f;
        float b = bhi(u) + qb; b = b > 0.f ? b : 0.f;
        sA += a; sB += b; qA += a * a; qB += b * b;
        mxA = fmaxf(mxA, a); mxB = fmaxf(mxB, b);
        mnA = fminf(mnA, a); mnB = fminf(mnB, b);
    }

    float inv = 1.0f / (float)(s1 - s0);   // deg >= 1 guaranteed (self-loops)
    float mA = sA * inv, mB = sB * inv;
    float vA = qA * inv - mA * mA; vA = vA > 0.f ? vA : 0.f;
    float vB = qB * inv - mB * mB; vB = vB > 0.f ? vB : 0.f;
    float stA = sqrtf(vA + EPS_V), stB = sqrtf(vB + EPS_V);

    unsigned* ag = (unsigned*)(aggbf + (long)n * 512);
    ag[lane]       = pk2(mA, mB);
    ag[64 + lane]  = pk2(mxA, mxB);
    ag[128 + lane] = pk2(mnA, mnB);
    ag[192 + lane] = pk2(stA, stB);
}

// ---------------------------------------------------------------- fused post + mix per node (64-row tiles)
// identity: x@W_post = [h|agg]@[W0;W1] + amp*(agg@W2) + att*(agg@W3)   (amp/att per-node scalars)
// wpostT k-order is already [W0|W1|W2|W3]; A-staging is a pure copy (no scaling VALU).
__global__ __launch_bounds__(256) void node_kernel(
    const float* __restrict__ h, const short* __restrict__ hbf, const short* __restrict__ aggbf,
    const int* __restrict__ degc, const short* __restrict__ wpostT, const float* __restrict__ bpost,
    const short* __restrict__ wmixT, const float* __restrict__ bmix, float* __restrict__ out)
{
    __shared__ __align__(16) short As[64][72];
    __shared__ __align__(16) short Bs[384][72];   // [0:128)=B1, [128:256)=B2, [256:384)=B3
    __shared__ float sAmp[64], sAtt[64];

    const int tid = threadIdx.x;
    const int bn = blockIdx.x * 64;
    if (tid < 64) {
        int n = bn + tid; if (n >= N_NODES) n = N_NODES - 1;
        float d = (float)degc[n];
        float ld = logf(d + 1.0f);
        sAmp[tid] = ld * (1.0f / AVG_D_LOG);
        sAtt[tid] = AVG_D_LOG / ld;
    }

    const int lane = tid & 63, wv = tid >> 6;
    const int lm = lane & 15, quad = lane >> 4;
    const int arow = wv * 16 + lm;

    f32x4 Y1[8], Y2[8], Y3[8];
#pragma unroll
    for (int b = 0; b < 8; b++) {
        Y1[b] = (f32x4){0.f, 0.f, 0.f, 0.f};
        Y2[b] = (f32x4){0.f, 0.f, 0.f, 0.f};
        Y3[b] = (f32x4){0.f, 0.f, 0.f, 0.f};
    }

    // ---- post GEMM: 10 chunks of 64 over A = [hbf | aggbf]
    for (int c = 0; c < 10; c++) {
        __syncthreads();
#pragma unroll
        for (int t = 0; t < 2; t++) {          // A: 64 rows x 64 k
            int q = tid + t * 256;
            int m = q >> 3, seg = q & 7;
            int n = bn + m; if (n >= N_NODES) n = N_NODES - 1;
            const short* src = (c < 2) ? (hbf + (long)n * 128 + c * 64 + seg * 8)
                                       : (aggbf + (long)n * 512 + (c - 2) * 64 + seg * 8);
            *(int4*)&As[m][seg * 8] = *(const int4*)src;
        }
#pragma unroll
        for (int t = 0; t < 4; t++) {          // B1: W[0:640) slice c
            int q = tid + t * 256;
            int n = q >> 3, seg = q & 7;
            *(int4*)&Bs[n][seg * 8] = *(const int4*)(wpostT + n * 1664 + c * 64 + seg * 8);
        }
        if (c >= 2) {
            const int k2 = 640 + (c - 2) * 64, k3 = 1152 + (c - 2) * 64;
#pragma unroll
            for (int t = 0; t < 4; t++) {
                int q = tid + t * 256;
                int n = q >> 3, seg = q & 7;
                *(int4*)&Bs[128 + n][seg * 8] = *(const int4*)(wpostT + n * 1664 + k2 + seg * 8);
                *(int4*)&Bs[256 + n][seg * 8] = *(const int4*)(wpostT + n * 1664 + k3 + seg * 8);
            }
        }
        __syncthreads();
        if (c >= 2) {
#pragma unroll
            for (int ks = 0; ks < 2; ks++) {
                const int ko = ks * 32 + quad * 8;
                bf16x8 a = *(const bf16x8*)&As[arow][ko];
#pragma unroll
                for (int ct = 0; ct < 8; ct++) {
                    bf16x8 b1 = *(const bf16x8*)&Bs[ct * 16 + lm][ko];
                    bf16x8 b2 = *(const bf16x8*)&Bs[128 + ct * 16 + lm][ko];
                    bf16x8 b3 = *(const bf16x8*)&Bs[256 + ct * 16 + lm][ko];
                    Y1[ct] = __builtin_amdgcn_mfma_f32_16x16x32_bf16(b1, a, Y1[ct], 0, 0, 0);
                    Y2[ct] = __builtin_amdgcn_mfma_f32_16x16x32_bf16(b2, a, Y2[ct], 0, 0, 0);
                    Y3[ct] = __builtin_amdgcn_mfma_f32_16x16x32_bf16(b3, a, Y3[ct], 0, 0, 0);
                }
            }
        } else {
#pragma unroll
            for (int ks = 0; ks < 2; ks++) {
                const int ko = ks * 32 + quad * 8;
                bf16x8 a = *(const bf16x8*)&As[arow][ko];
#pragma unroll
                for (int ct = 0; ct < 8; ct++) {
                    bf16x8 b1 = *(const bf16x8*)&Bs[ct * 16 + lm][ko];
                    Y1[ct] = __builtin_amdgcn_mfma_f32_16x16x32_bf16(b1, a, Y1[ct], 0, 0, 0);
                }
            }
        }
    }

    // hp = relu(Y1 + amp*Y2 + att*Y3 + b_post)   (in Y1)
    {
        const float amp = sAmp[arow], att = sAtt[arow];
#pragma unroll
        for (int ct = 0; ct < 8; ct++) {
            float4 bv = *(const float4*)(bpost + ct * 16 + quad * 4);
            float v0 = Y1[ct][0] + amp * Y2[ct][0] + att * Y3[ct][0] + bv.x;
            float v1 = Y1[ct][1] + amp * Y2[ct][1] + att * Y3[ct][1] + bv.y;
            float v2 = Y1[ct][2] + amp * Y2[ct][2] + att * Y3[ct][2] + bv.z;
            float v3 = Y1[ct][3] + amp * Y2[ct][3] + att * Y3[ct][3] + bv.w;
            Y1[ct][0] = v0 > 0.f ? v0 : 0.f;
            Y1[ct][1] = v1 > 0.f ? v1 : 0.f;
            Y1[ct][2] = v2 > 0.f ? v2 : 0.f;
            Y1[ct][3] = v3 > 0.f ? v3 : 0.f;
        }
    }

    // ---- mix GEMM: K = 128 (hp), 2 chunks
    f32x4 acc2[8];
#pragma unroll
    for (int b = 0; b < 8; b++) acc2[b] = (f32x4){0.f, 0.f, 0.f, 0.f};

#pragma unroll
    for (int kc = 0; kc < 2; kc++) {
        __syncthreads();
#pragma unroll
        for (int ctl = 0; ctl < 4; ctl++) {    // restage hp cols [kc*64, +64) from registers
            int ct = kc * 4 + ctl;
            int col = ctl * 16 + quad * 4;
            int2 pkd;
            pkd.x = (int)pk2(Y1[ct][0], Y1[ct][1]);
            pkd.y = (int)pk2(Y1[ct][2], Y1[ct][3]);
            *(int2*)&As[arow][col] = pkd;
        }
#pragma unroll
        for (int t = 0; t < 4; t++) {          // B: ALL 128 wmixT rows x 64 k  (t<4 — round-4 bug was t<2)
            int q = tid + t * 256;
            int n = q >> 3, seg = q & 7;
            *(int4*)&Bs[n][seg * 8] = *(const int4*)(wmixT + n * 128 + kc * 64 + seg * 8);
        }
        __syncthreads();
#pragma unroll
        for (int ks = 0; ks < 2; ks++) {
            const int ko = ks * 32 + quad * 8;
            bf16x8 a = *(const bf16x8*)&As[arow][ko];
#pragma unroll
            for (int ct = 0; ct < 8; ct++) {
                bf16x8 b = *(const bf16x8*)&Bs[ct * 16 + lm][ko];
                acc2[ct] = __builtin_amdgcn_mfma_f32_16x16x32_bf16(b, a, acc2[ct], 0, 0, 0);
            }
        }
    }

    // epilogue: out = h + leaky_relu(acc2 + b_mix)
    {
        int n = bn + arow;
        if (n < N_NODES) {
#pragma unroll
            for (int ct = 0; ct < 8; ct++) {
                int col = ct * 16 + quad * 4;
                float4 bv = *(const float4*)(bmix + col);
                float4 hv = *(const float4*)(h + (long)n * 128 + col);
                float4 o;
                float v0 = acc2[ct][0] + bv.x; v0 = v0 > 0.f ? v0 : 0.01f * v0; o.x = hv.x + v0;
                float v1 = acc2[ct][1] + bv.y; v1 = v1 > 0.f ? v1 : 0.01f * v1; o.y = hv.y + v1;
                float v2 = acc2[ct][2] + bv.z; v2 = v2 > 0.f ? v2 : 0.01f * v2; o.z = hv.z + v2;
                float v3 = acc2[ct][3] + bv.w; v3 = v3 > 0.f ? v3 : 0.01f * v3; o.w = hv.w + v3;
                *(float4*)(out + (long)n * 128 + col) = o;
            }
        }
    }
}

extern "C" void kernel_launch(void* const* d_in, const int* in_sizes, int n_in,
                              void* d_out, int out_size, void* d_ws, size_t ws_size,
                              hipStream_t stream) {
    const float* h     = (const float*)d_in[0];
    const int*   esrc  = (const int*)d_in[1];
    const int*   edst  = (const int*)d_in[2];
    const float* Wpre  = (const float*)d_in[3];
    const float* bpre  = (const float*)d_in[4];
    const float* Wpost = (const float*)d_in[5];
    const float* bpost = (const float*)d_in[6];
    const float* Wmix  = (const float*)d_in[7];
    const float* bmix  = (const float*)d_in[8];
    float* out = (float*)d_out;
    char* ws = (char*)d_ws;

    short* PQ     = (short*)(ws + PQ_B);
    short* aggbf  = (short*)(ws + AGG_B);
    short* hbf    = (short*)(ws + HBF_B);
    short* wpreT2 = (short*)(ws + WPRET2_B);
    short* wpostT = (short*)(ws + WPOSTT_B);
    short* wmixT  = (short*)(ws + WMIXT_B);
    int*   degc   = (int*)(ws + DEGC_B);
    int*   off    = (int*)(ws + OFF_B);
    int*   cursor = (int*)(ws + CUR_B);
    int*   srcs   = (int*)(ws + SRCS_B);
    int*   bsum   = (int*)(ws + BSUM_B);

    prep_kernel<<<26415, 256, 0, stream>>>(h, Wpre, Wpost, Wmix, hbf, wpreT2, wpostT, wmixT, degc, cursor);
    hist_kernel<<<(N_EDGES + 255) / 256, 256, 0, stream>>>(edst, degc);
    scan1_kernel<<<NB_SCAN, 256, 0, stream>>>(degc, bsum);
    scan2_kernel<<<1, 256, 0, stream>>>(bsum, off);
    scan3_kernel<<<NB_SCAN, 256, 0, stream>>>(degc, bsum, off);
    scatter_kernel<<<(N_EDGES + 255) / 256, 256, 0, stream>>>(esrc, edst, off, cursor, srcs);
    gemm_pq_kernel<<<(N_NODES + 127) / 128, 256, 0, stream>>>(hbf, wpreT2, bpre, PQ);
    edgestats_kernel<<<N_NODES / 4, 256, 0, stream>>>(PQ, srcs, off, aggbf);
    node_kernel<<<(N_NODES + 63) / 64, 256, 0, stream>>>(h, hbf, aggbf, degc, wpostT, bpost, wmixT, bmix, out);
}

// Round 7
// 299.557 us; speedup vs baseline: 1.2968x; 1.2968x over previous
//
#include <hip/hip_runtime.h>
#include <hip/hip_bf16.h>

#define N_NODES 50000
#define N_EDGES 600000
#define D 128
#define NB_SCAN 196  // ceil(50000/256)

constexpr float AVG_D_LOG = 1.6094379124341003f;  // log(5)
constexpr float EPS_V = 1e-5f;

// ---- workspace byte offsets (total ~93.1 MB)
#define PQ_B     0ul           // bf16 [50000][256]  P|Q rows     = 25,600,000
#define AGG_B    25600000ul    // bf16 [50000][512]  mean|max|min|std = 51,200,000
#define HBF_B    76800000ul    // bf16 [50000][128]
#define WPRET2_B 89600000ul    // bf16 [256][128]   (P cols | Q cols, [n][k])
#define WPOSTT_B 89665536ul    // bf16 [128][1664]
#define WMIXT_B  90091520ul    // bf16 [128][128]
#define DEGC_B   90124288ul    // int  [50000]
#define OFF_B    90324288ul    // int  [50016]
#define CUR_B    90524352ul    // int  [50000]
#define SRCS_B   90724352ul    // int  [600000]  src ids in dst-sorted order
#define BSUM_B   93124352ul    // int  [256]

typedef __attribute__((ext_vector_type(8))) short bf16x8;
typedef __attribute__((ext_vector_type(4))) float f32x4;

__device__ __forceinline__ short f2b(float f) {
    unsigned u = __builtin_bit_cast(unsigned, f);
    u += 0x7fffu + ((u >> 16) & 1u);   // RNE
    return (short)(u >> 16);
}
__device__ __forceinline__ unsigned pk2(float a, float b) {
    return (unsigned)(unsigned short)f2b(a) | ((unsigned)(unsigned short)f2b(b) << 16);
}
__device__ __forceinline__ float blo(unsigned u) { return __uint_as_float(u << 16); }
__device__ __forceinline__ float bhi(unsigned u) { return __uint_as_float(u & 0xffff0000u); }

// ---------------------------------------------------------------- prep
__global__ __launch_bounds__(256) void prep_kernel(
    const float* __restrict__ h, const float* __restrict__ Wpre,
    const float* __restrict__ Wpost, const float* __restrict__ Wmix,
    short* __restrict__ hbf, short* __restrict__ wpreT2,
    short* __restrict__ wpostT, short* __restrict__ wmixT,
    int* __restrict__ degc, int* __restrict__ cursor)
{
    long i = (long)blockIdx.x * 256 + threadIdx.x;
    if (i < 6400000) { hbf[i] = f2b(h[i]); return; }
    i -= 6400000;
    if (i < 32768) {  // wpreT2[n][k]: n<128 -> Wpre[k][n] (top); n>=128 -> Wpre[k+128][n-128]
        int n = i >> 7, k = i & 127;
        float v = (n < 128) ? Wpre[k * 128 + n] : Wpre[(k + 128) * 128 + (n - 128)];
        wpreT2[n * 128 + k] = f2b(v);
        return;
    }
    i -= 32768;
    if (i < 212992) { int k = i >> 7, n = i & 127; wpostT[n * 1664 + k] = f2b(Wpost[k * 128 + n]); return; }
    i -= 212992;
    if (i < 16384) { int k = i >> 7, n = i & 127; wmixT[n * 128 + k] = f2b(Wmix[k * 128 + n]); return; }
    i -= 16384;
    if (i < N_NODES) { degc[i] = 0; return; }
    i -= N_NODES;
    if (i < N_NODES) cursor[i] = 0;
}

// ---------------------------------------------------------------- degree histogram
__global__ __launch_bounds__(256) void hist_kernel(const int* __restrict__ edst, int* __restrict__ degc) {
    int e = blockIdx.x * 256 + threadIdx.x;
    if (e < N_EDGES) atomicAdd(&degc[edst[e]], 1);
}

// ---------------------------------------------------------------- scan
__global__ __launch_bounds__(256) void scan1_kernel(const int* __restrict__ degc, int* __restrict__ bsum) {
    int n = blockIdx.x * 256 + threadIdx.x;
    int v = (n < N_NODES) ? degc[n] : 0;
#pragma unroll
    for (int o = 32; o > 0; o >>= 1) v += __shfl_down(v, o);
    __shared__ int w4[4];
    if ((threadIdx.x & 63) == 0) w4[threadIdx.x >> 6] = v;
    __syncthreads();
    if (threadIdx.x == 0) bsum[blockIdx.x] = w4[0] + w4[1] + w4[2] + w4[3];
}

// parallel exclusive scan of the 196 block sums (one block)
__global__ __launch_bounds__(256) void scan2_kernel(int* __restrict__ bsum, int* __restrict__ off) {
    __shared__ int sd[256];
    int tid = threadIdx.x;
    int v = (tid < NB_SCAN) ? bsum[tid] : 0;
    sd[tid] = v;
    __syncthreads();
    for (int o = 1; o < 256; o <<= 1) {
        int t = (tid >= o) ? sd[tid - o] : 0;
        __syncthreads();
        sd[tid] += t;
        __syncthreads();
    }
    if (tid < NB_SCAN) bsum[tid] = sd[tid] - v;   // exclusive
    if (tid == 0) off[N_NODES] = sd[255];         // total = N_EDGES
}

__global__ __launch_bounds__(256) void scan3_kernel(const int* __restrict__ degc,
                                                    const int* __restrict__ bsum, int* __restrict__ off) {
    __shared__ int sd[256];
    int tid = threadIdx.x;
    int n = blockIdx.x * 256 + tid;
    int v = (n < N_NODES) ? degc[n] : 0;
    sd[tid] = v;
    __syncthreads();
    for (int o = 1; o < 256; o <<= 1) {
        int t = (tid >= o) ? sd[tid - o] : 0;
        __syncthreads();
        sd[tid] += t;
        __syncthreads();
    }
    if (n < N_NODES) off[n] = sd[tid] - v + bsum[blockIdx.x];
}

// ---------------------------------------------------------------- scatter srcs into dst-sorted order
__global__ __launch_bounds__(256) void scatter_kernel(const int* __restrict__ esrc, const int* __restrict__ edst,
                                                      const int* __restrict__ off, int* __restrict__ cursor,
                                                      int* __restrict__ srcs) {
    int e = blockIdx.x * 256 + threadIdx.x;
    if (e < N_EDGES) {
        int d = edst[e];
        int p = off[d] + atomicAdd(&cursor[d], 1);
        srcs[p] = esrc[e];
    }
}

// ---------------------------------------------------------------- PQ = h @ [Wtop | Wbot] (+bias on Q)
__global__ __launch_bounds__(256) void gemm_pq_kernel(
    const short* __restrict__ hbf, const short* __restrict__ wpreT2,
    const float* __restrict__ bpre, short* __restrict__ PQ)
{
    __shared__ __align__(16) short As[128][72];
    __shared__ __align__(16) short Bs[256][72];

    const int tid = threadIdx.x;
    const int bn = blockIdx.x * 128;
    const int lane = tid & 63, wv = tid >> 6;
    const int lm = lane & 15, quad = lane >> 4;

    f32x4 acc[2][16];
#pragma unroll
    for (int a = 0; a < 2; a++)
#pragma unroll
        for (int b = 0; b < 16; b++) acc[a][b] = (f32x4){0.f, 0.f, 0.f, 0.f};

#pragma unroll
    for (int kc = 0; kc < 2; kc++) {
        __syncthreads();
#pragma unroll
        for (int t = 0; t < 4; t++) {
            int q = tid + t * 256;
            int m = q >> 3, seg = q & 7;
            int n = bn + m; if (n >= N_NODES) n = N_NODES - 1;
            *(int4*)&As[m][seg * 8] = *(const int4*)(hbf + (long)n * 128 + kc * 64 + seg * 8);
        }
#pragma unroll
        for (int t = 0; t < 8; t++) {
            int q = tid + t * 256;
            int n = q >> 3, seg = q & 7;
            *(int4*)&Bs[n][seg * 8] = *(const int4*)(wpreT2 + n * 128 + kc * 64 + seg * 8);
        }
        __syncthreads();
#pragma unroll
        for (int ks = 0; ks < 2; ks++) {
            const int ko = ks * 32 + quad * 8;
            bf16x8 a0 = *(const bf16x8*)&As[wv * 32 + lm][ko];
            bf16x8 a1 = *(const bf16x8*)&As[wv * 32 + 16 + lm][ko];
#pragma unroll
            for (int ct = 0; ct < 16; ct++) {
                bf16x8 b = *(const bf16x8*)&Bs[ct * 16 + lm][ko];
                acc[0][ct] = __builtin_amdgcn_mfma_f32_16x16x32_bf16(b, a0, acc[0][ct], 0, 0, 0);
                acc[1][ct] = __builtin_amdgcn_mfma_f32_16x16x32_bf16(b, a1, acc[1][ct], 0, 0, 0);
            }
        }
    }

    // epilogue: row = node, col 0-127 = P (no bias), 128-255 = Q (+bias)
#pragma unroll
    for (int rt = 0; rt < 2; rt++) {
        int row = wv * 32 + rt * 16 + lm;
        int n = bn + row;
        if (n >= N_NODES) continue;
        short* dst = PQ + (long)n * 256;
#pragma unroll
        for (int ct = 0; ct < 16; ct++) {
            int col = ct * 16 + quad * 4;
            float v0 = acc[rt][ct][0], v1 = acc[rt][ct][1], v2 = acc[rt][ct][2], v3 = acc[rt][ct][3];
            if (ct >= 8) {
                float4 bv = *(const float4*)(bpre + (col - 128));
                v0 += bv.x; v1 += bv.y; v2 += bv.z; v3 += bv.w;
            }
            int2 pkd; pkd.x = (int)pk2(v0, v1); pkd.y = (int)pk2(v2, v3);
            *(int2*)(dst + col) = pkd;
        }
    }
}

// ---------------------------------------------------------------- fused edge compute + stats: one wave per node
__global__ __launch_bounds__(256) void edgestats_kernel(
    const short* __restrict__ PQ, const int* __restrict__ srcs,
    const int* __restrict__ off, short* __restrict__ aggbf)
{
    const int wv = threadIdx.x >> 6, lane = threadIdx.x & 63;
    const int n = blockIdx.x * 4 + wv;            // grid 12500 * 4 waves = 50000
    const unsigned* Pb = (const unsigned*)PQ;     // u32 view: row = 128 u32 (P=0..63, Q=64..127)

    const int s0 = __builtin_amdgcn_readfirstlane(off[n]);
    const int s1 = __builtin_amdgcn_readfirstlane(off[n + 1]);

    unsigned qu = Pb[(long)n * 128 + 64 + lane];
    const float qa = blo(qu), qb = bhi(qu);

    float sA = 0.f, sB = 0.f, qA = 0.f, qB = 0.f;
    float mxA = -1e30f, mxB = -1e30f, mnA = 1e30f, mnB = 1e30f;

    int p = s0;
    for (; p + 4 <= s1; p += 4) {
        int i0 = srcs[p], i1 = srcs[p + 1], i2 = srcs[p + 2], i3 = srcs[p + 3];
        unsigned u0 = Pb[(long)i0 * 128 + lane];
        unsigned u1 = Pb[(long)i1 * 128 + lane];
        unsigned u2 = Pb[(long)i2 * 128 + lane];
        unsigned u3 = Pb[(long)i3 * 128 + lane];
#pragma unroll
        for (int j = 0; j < 4; j++) {
            unsigned u = (j == 0) ? u0 : (j == 1) ? u1 : (j == 2) ? u2 : u3;
            float a = blo(u) + qa; a = a > 0.f ? a : 0.f;
            float b = bhi(u) + qb; b = b > 0.f ? b : 0.f;
            sA += a; sB += b; qA += a * a; qB += b * b;
            mxA = fmaxf(mxA, a); mxB = fmaxf(mxB, b);
            mnA = fminf(mnA, a); mnB = fminf(mnB, b);
        }
    }
    for (; p < s1; p++) {
        unsigned u = Pb[(long)srcs[p] * 128 + lane];
        float a = blo(u) + qa; a = a > 0.f ? a : 0.f;
        float b = bhi(u) + qb; b = b > 0.f ? b : 0.f;
        sA += a; sB += b; qA += a * a; qB += b * b;
        mxA = fmaxf(mxA, a); mxB = fmaxf(mxB, b);
        mnA = fminf(mnA, a); mnB = fminf(mnB, b);
    }

    float inv = 1.0f / (float)(s1 - s0);   // deg >= 1 guaranteed (self-loops)
    float mA = sA * inv, mB = sB * inv;
    float vA = qA * inv - mA * mA; vA = vA > 0.f ? vA : 0.f;
    float vB = qB * inv - mB * mB; vB = vB > 0.f ? vB : 0.f;
    float stA = sqrtf(vA + EPS_V), stB = sqrtf(vB + EPS_V);

    unsigned* ag = (unsigned*)(aggbf + (long)n * 512);
    ag[lane]       = pk2(mA, mB);
    ag[64 + lane]  = pk2(mxA, mxB);
    ag[128 + lane] = pk2(mnA, mnB);
    ag[192 + lane] = pk2(stA, stB);
}

// ---------------------------------------------------------------- fused post + mix per node (64-row tile,
// single 128-row B panel per chunk — round-3 staging structure at 2x grid; scale applied in A staging)
__global__ __launch_bounds__(256) void node_kernel(
    const float* __restrict__ h, const short* __restrict__ hbf, const short* __restrict__ aggbf,
    const int* __restrict__ degc, const short* __restrict__ wpostT, const float* __restrict__ bpost,
    const short* __restrict__ wmixT, const float* __restrict__ bmix, float* __restrict__ out)
{
    __shared__ __align__(16) short As[64][72];     //  9.2 KB
    __shared__ __align__(16) short Bs[128][72];    // 18.4 KB  (total ~28 KB -> 5 blocks/CU LDS cap)
    __shared__ float sAmp[64], sAtt[64];

    const int tid = threadIdx.x;
    const int bn = blockIdx.x * 64;
    if (tid < 64) {
        int n = bn + tid; if (n >= N_NODES) n = N_NODES - 1;
        float d = (float)degc[n];
        float ld = logf(d + 1.0f);
        sAmp[tid] = ld * (1.0f / AVG_D_LOG);
        sAtt[tid] = AVG_D_LOG / ld;
    }
    __syncthreads();

    const int lane = tid & 63, wv = tid >> 6;
    const int lm = lane & 15, quad = lane >> 4;
    const int arow = wv * 16 + lm;                 // wave wv owns node rows [wv*16, wv*16+16)

    f32x4 acc[8];
#pragma unroll
    for (int b = 0; b < 8; b++) acc[b] = (f32x4){0.f, 0.f, 0.f, 0.f};

    // ---- post GEMM: K = 1664 = 26 chunks of 64;  A cols: [h(2) | (agg,amp*agg,att*agg)(24)]
    for (int c = 0; c < 26; c++) {
        __syncthreads();
        const int r = c >> 1;            // region 0=h, 1..12 = agg*scaler
        const int half = (c & 1) * 64;
        // stage A: 64 rows x 64 k = 512 int4, 2 per thread
#pragma unroll
        for (int t = 0; t < 2; t++) {
            int q = tid + t * 256;
            int m = q >> 3, seg = q & 7;
            int n = bn + m; if (n >= N_NODES) n = N_NODES - 1;
            int4 v;
            if (r == 0) {
                v = *(const int4*)(hbf + (long)n * 128 + half + seg * 8);
            } else {
                int a = (r - 1) & 3, s = (r - 1) >> 2;
                v = *(const int4*)(aggbf + (long)n * 512 + a * 128 + half + seg * 8);
                if (s) {
                    float sc = (s == 1) ? sAmp[m] : sAtt[m];
                    unsigned* pu = (unsigned*)&v;
#pragma unroll
                    for (int j = 0; j < 4; j++) {
                        unsigned u = pu[j];
                        pu[j] = pk2(blo(u) * sc, bhi(u) * sc);
                    }
                }
            }
            *(int4*)&As[m][seg * 8] = v;
        }
        // stage B: 128 out-channel rows x 64 k
#pragma unroll
        for (int t = 0; t < 4; t++) {
            int q = tid + t * 256;
            int n = q >> 3, seg = q & 7;
            *(int4*)&Bs[n][seg * 8] = *(const int4*)(wpostT + n * 1664 + c * 64 + seg * 8);
        }
        __syncthreads();
#pragma unroll
        for (int ks = 0; ks < 2; ks++) {
            const int ko = ks * 32 + quad * 8;
            bf16x8 a = *(const bf16x8*)&As[arow][ko];
#pragma unroll
            for (int ct = 0; ct < 8; ct++) {
                bf16x8 b = *(const bf16x8*)&Bs[ct * 16 + lm][ko];
                acc[ct] = __builtin_amdgcn_mfma_f32_16x16x32_bf16(b, a, acc[ct], 0, 0, 0);
            }
        }
    }

    // hp = relu(acc + b_post); lane holds node = arow, cols ct*16+quad*4..+3
#pragma unroll
    for (int ct = 0; ct < 8; ct++) {
        float4 bv = *(const float4*)(bpost + ct * 16 + quad * 4);
        float v0 = acc[ct][0] + bv.x; acc[ct][0] = v0 > 0.f ? v0 : 0.f;
        float v1 = acc[ct][1] + bv.y; acc[ct][1] = v1 > 0.f ? v1 : 0.f;
        float v2 = acc[ct][2] + bv.z; acc[ct][2] = v2 > 0.f ? v2 : 0.f;
        float v3 = acc[ct][3] + bv.w; acc[ct][3] = v3 > 0.f ? v3 : 0.f;
    }

    // ---- mix GEMM: K = 128 (hp), 2 chunks
    f32x4 acc2[8];
#pragma unroll
    for (int b = 0; b < 8; b++) acc2[b] = (f32x4){0.f, 0.f, 0.f, 0.f};

#pragma unroll
    for (int kc = 0; kc < 2; kc++) {
        __syncthreads();
        // restage hp cols [kc*64, +64) from registers (packed 8B writes)
#pragma unroll
        for (int ctl = 0; ctl < 4; ctl++) {
            int ct = kc * 4 + ctl;
            int col = ctl * 16 + quad * 4;
            int2 pkd;
            pkd.x = (int)pk2(acc[ct][0], acc[ct][1]);
            pkd.y = (int)pk2(acc[ct][2], acc[ct][3]);
            *(int2*)&As[arow][col] = pkd;
        }
        // B: ALL 128 wmixT rows x 64 k
#pragma unroll
        for (int t = 0; t < 4; t++) {
            int q = tid + t * 256;
            int n = q >> 3, seg = q & 7;
            *(int4*)&Bs[n][seg * 8] = *(const int4*)(wmixT + n * 128 + kc * 64 + seg * 8);
        }
        __syncthreads();
#pragma unroll
        for (int ks = 0; ks < 2; ks++) {
            const int ko = ks * 32 + quad * 8;
            bf16x8 a = *(const bf16x8*)&As[arow][ko];
#pragma unroll
            for (int ct = 0; ct < 8; ct++) {
                bf16x8 b = *(const bf16x8*)&Bs[ct * 16 + lm][ko];
                acc2[ct] = __builtin_amdgcn_mfma_f32_16x16x32_bf16(b, a, acc2[ct], 0, 0, 0);
            }
        }
    }

    // epilogue: out = h + leaky_relu(acc2 + b_mix); float4 stores
    {
        int n = bn + arow;
        if (n < N_NODES) {
#pragma unroll
            for (int ct = 0; ct < 8; ct++) {
                int col = ct * 16 + quad * 4;
                float4 bv = *(const float4*)(bmix + col);
                float4 hv = *(const float4*)(h + (long)n * 128 + col);
                float4 o;
                float v0 = acc2[ct][0] + bv.x; v0 = v0 > 0.f ? v0 : 0.01f * v0; o.x = hv.x + v0;
                float v1 = acc2[ct][1] + bv.y; v1 = v1 > 0.f ? v1 : 0.01f * v1; o.y = hv.y + v1;
                float v2 = acc2[ct][2] + bv.z; v2 = v2 > 0.f ? v2 : 0.01f * v2; o.z = hv.z + v2;
                float v3 = acc2[ct][3] + bv.w; v3 = v3 > 0.f ? v3 : 0.01f * v3; o.w = hv.w + v3;
                *(float4*)(out + (long)n * 128 + col) = o;
            }
        }
    }
}

extern "C" void kernel_launch(void* const* d_in, const int* in_sizes, int n_in,
                              void* d_out, int out_size, void* d_ws, size_t ws_size,
                              hipStream_t stream) {
    const float* h     = (const float*)d_in[0];
    const int*   esrc  = (const int*)d_in[1];
    const int*   edst  = (const int*)d_in[2];
    const float* Wpre  = (const float*)d_in[3];
    const float* bpre  = (const float*)d_in[4];
    const float* Wpost = (const float*)d_in[5];
    const float* bpost = (const float*)d_in[6];
    const float* Wmix  = (const float*)d_in[7];
    const float* bmix  = (const float*)d_in[8];
    float* out = (float*)d_out;
    char* ws = (char*)d_ws;

    short* PQ     = (short*)(ws + PQ_B);
    short* aggbf  = (short*)(ws + AGG_B);
    short* hbf    = (short*)(ws + HBF_B);
    short* wpreT2 = (short*)(ws + WPRET2_B);
    short* wpostT = (short*)(ws + WPOSTT_B);
    short* wmixT  = (short*)(ws + WMIXT_B);
    int*   degc   = (int*)(ws + DEGC_B);
    int*   off    = (int*)(ws + OFF_B);
    int*   cursor = (int*)(ws + CUR_B);
    int*   srcs   = (int*)(ws + SRCS_B);
    int*   bsum   = (int*)(ws + BSUM_B);

    prep_kernel<<<26415, 256, 0, stream>>>(h, Wpre, Wpost, Wmix, hbf, wpreT2, wpostT, wmixT, degc, cursor);
    hist_kernel<<<(N_EDGES + 255) / 256, 256, 0, stream>>>(edst, degc);
    scan1_kernel<<<NB_SCAN, 256, 0, stream>>>(degc, bsum);
    scan2_kernel<<<1, 256, 0, stream>>>(bsum, off);
    scan3_kernel<<<NB_SCAN, 256, 0, stream>>>(degc, bsum, off);
    scatter_kernel<<<(N_EDGES + 255) / 256, 256, 0, stream>>>(esrc, edst, off, cursor, srcs);
    gemm_pq_kernel<<<(N_NODES + 127) / 128, 256, 0, stream>>>(hbf, wpreT2, bpre, PQ);
    edgestats_kernel<<<N_NODES / 4, 256, 0, stream>>>(PQ, srcs, off, aggbf);
    node_kernel<<<(N_NODES + 63) / 64, 256, 0, stream>>>(h, hbf, aggbf, degc, wpostT, bpost, wmixT, bmix, out);
}